// Round 1
// baseline (1534.565 us; speedup 1.0000x reference)
//
#include <hip/hip_runtime.h>

// BilinearGridSample: img (N=8, C=64, H=256, W=256) f32, points (N, 384, 384, 2) f32
// out (N, C, 384, 384) f32. mmcv bilinear_grid_sample, align_corners=False,
// zero padding (pad-by-1 + clamp == zero contribution for OOB corners).

#define CC 64
#define HH 256
#define WW 256

__global__ __launch_bounds__(256) void grid_sample_kernel(
    const float* __restrict__ img,     // (N, C, H, W)
    const float* __restrict__ points,  // (N, GH, GW, 2) -> flat (N*P, 2)
    float* __restrict__ out,           // (N, C, P)
    int total, int P)
{
    int tid = blockIdx.x * blockDim.x + threadIdx.x;
    if (tid >= total) return;
    int n = tid / P;
    int p = tid - n * P;

    float2 pt = ((const float2*)points)[tid];
    float x = ((pt.x + 1.0f) * (float)WW - 1.0f) * 0.5f;
    float y = ((pt.y + 1.0f) * (float)HH - 1.0f) * 0.5f;

    float x0f = floorf(x);
    float y0f = floorf(y);
    float fx = x - x0f;   // x - x0
    float fy = y - y0f;   // y - y0
    int x0 = (int)x0f;
    int y0 = (int)y0f;
    int x1 = x0 + 1;
    int y1 = y0 + 1;

    // corner validity (pad-by-1 + clamp semantics == OOB corner contributes 0)
    bool vx0 = (x0 >= 0) && (x0 < WW);
    bool vx1 = (x1 >= 0) && (x1 < WW);
    bool vy0 = (y0 >= 0) && (y0 < HH);
    bool vy1 = (y1 >= 0) && (y1 < HH);

    float wa = (1.0f - fx) * (1.0f - fy);  // (y0, x0)
    float wb = (1.0f - fx) * fy;           // (y1, x0)
    float wc = fx * (1.0f - fy);           // (y0, x1)
    float wd = fx * fy;                    // (y1, x1)

    wa = (vx0 && vy0) ? wa : 0.0f;
    wb = (vx0 && vy1) ? wb : 0.0f;
    wc = (vx1 && vy0) ? wc : 0.0f;
    wd = (vx1 && vy1) ? wd : 0.0f;

    // clamp addresses into range; zeroed weight makes the value irrelevant
    int cx0 = min(max(x0, 0), WW - 1);
    int cx1 = min(max(x1, 0), WW - 1);
    int cy0 = min(max(y0, 0), HH - 1);
    int cy1 = min(max(y1, 0), HH - 1);

    const float* imgn = img + (size_t)n * CC * HH * WW;
    int ia = cy0 * WW + cx0;
    int ib = cy1 * WW + cx0;
    int ic = cy0 * WW + cx1;
    int id = cy1 * WW + cx1;

    float* outp = out + (size_t)n * CC * P + p;

    #pragma unroll 4
    for (int c = 0; c < CC; ++c) {
        const float* plane = imgn + c * (HH * WW);
        float Ia = plane[ia];
        float Ib = plane[ib];
        float Ic = plane[ic];
        float Id = plane[id];
        float v = Ia * wa + Ib * wb + Ic * wc + Id * wd;
        __builtin_nontemporal_store(v, outp + c * P);
    }
}

extern "C" void kernel_launch(void* const* d_in, const int* in_sizes, int n_in,
                              void* d_out, int out_size, void* d_ws, size_t ws_size,
                              hipStream_t stream) {
    const float* img = (const float*)d_in[0];
    const float* points = (const float*)d_in[1];
    float* out = (float*)d_out;

    const int N = 8;
    const int P = 384 * 384;          // points per batch
    const int total = N * P;          // 1,179,648 threads

    int block = 256;
    int grid = (total + block - 1) / block;
    grid_sample_kernel<<<grid, block, 0, stream>>>(img, points, out, total, P);
}

// Round 2
// 706.180 us; speedup vs baseline: 2.1731x; 2.1731x over previous
//
#include <hip/hip_runtime.h>

// BilinearGridSample: img (N=8, C=64, H=256, W=256) f32, points (N, 384, 384, 2) f32
// out (N, C, 384, 384) f32. mmcv bilinear_grid_sample, align_corners=False.
//
// Channel-major parallelization: block = 256 points, grid = (P/256, C/CPT, N).
// At any instant each XCD gathers from only a few 256-KiB planes -> L2-resident,
// img fetched from HBM ~once instead of 36x.

#define CC 64
#define HH 256
#define WW 256
#define PP (384 * 384)   // 147456, divisible by 256
#define CPT 2            // channels per thread

__global__ __launch_bounds__(256) void grid_sample_kernel(
    const float* __restrict__ img,     // (N, C, H, W)
    const float* __restrict__ points,  // (N, P, 2)
    float* __restrict__ out)           // (N, C, P)
{
    const int p  = blockIdx.x * 256 + threadIdx.x;  // point index
    const int c0 = blockIdx.y * CPT;                // first channel
    const int n  = blockIdx.z;

    float2 pt = ((const float2*)points)[(size_t)n * PP + p];
    float x = ((pt.x + 1.0f) * (float)WW - 1.0f) * 0.5f;
    float y = ((pt.y + 1.0f) * (float)HH - 1.0f) * 0.5f;

    float x0f = floorf(x);
    float y0f = floorf(y);
    float fx = x - x0f;
    float fy = y - y0f;
    int x0 = (int)x0f;
    int y0 = (int)y0f;
    int x1 = x0 + 1;
    int y1 = y0 + 1;

    bool vx0 = (x0 >= 0) && (x0 < WW);
    bool vx1 = (x1 >= 0) && (x1 < WW);
    bool vy0 = (y0 >= 0) && (y0 < HH);
    bool vy1 = (y1 >= 0) && (y1 < HH);

    float wa = (1.0f - fx) * (1.0f - fy);  // (y0, x0)
    float wb = (1.0f - fx) * fy;           // (y1, x0)
    float wc = fx * (1.0f - fy);           // (y0, x1)
    float wd = fx * fy;                    // (y1, x1)

    wa = (vx0 && vy0) ? wa : 0.0f;
    wb = (vx0 && vy1) ? wb : 0.0f;
    wc = (vx1 && vy0) ? wc : 0.0f;
    wd = (vx1 && vy1) ? wd : 0.0f;

    int cx0 = min(max(x0, 0), WW - 1);
    int cx1 = min(max(x1, 0), WW - 1);
    int cy0 = min(max(y0, 0), HH - 1);
    int cy1 = min(max(y1, 0), HH - 1);

    int ia = cy0 * WW + cx0;
    int ib = cy1 * WW + cx0;
    int ic = cy0 * WW + cx1;
    int id = cy1 * WW + cx1;

    const float* plane = img + ((size_t)(n * CC + c0)) * (HH * WW);
    float* outp = out + ((size_t)(n * CC + c0)) * PP + p;

    #pragma unroll
    for (int k = 0; k < CPT; ++k) {
        float Ia = plane[ia];
        float Ib = plane[ib];
        float Ic = plane[ic];
        float Id = plane[id];
        float v = Ia * wa + Ib * wb + Ic * wc + Id * wd;
        __builtin_nontemporal_store(v, outp);
        plane += HH * WW;
        outp  += PP;
    }
}

extern "C" void kernel_launch(void* const* d_in, const int* in_sizes, int n_in,
                              void* d_out, int out_size, void* d_ws, size_t ws_size,
                              hipStream_t stream) {
    const float* img = (const float*)d_in[0];
    const float* points = (const float*)d_in[1];
    float* out = (float*)d_out;

    dim3 grid(PP / 256, CC / CPT, 8);
    dim3 block(256, 1, 1);
    grid_sample_kernel<<<grid, block, 0, stream>>>(img, points, out);
}

// Round 3
// 304.382 us; speedup vs baseline: 5.0416x; 2.3200x over previous
//
#include <hip/hip_runtime.h>

// BilinearGridSample: img (N=8, C=64, H=256, W=256) f32, points (N,384,384,2) f32
// out (N, C, 384*384) f32.  mmcv bilinear_grid_sample, align_corners=False.
//
// Two-phase: (1) repack img -> channels-last bf16 in d_ws (N,H,W,C), RNE.
//            (2) per point: gather 4 corner runs of 64 contiguous bf16 (128 B)
//                as 8x uint4 each, unpack, weight, store 64 f32 outputs.
// Rationale: NCHW forces 4B-granular gathers (~420us of TA line-serialization);
// channels-last makes every fetched 64B line fully consumed.

#define CC 64
#define HH 256
#define WW 256
#define HWSZ (HH * WW)
#define PP (384 * 384)   // 147456, divisible by 256

__device__ __forceinline__ unsigned int bf16rne(float f) {
    unsigned int u = __float_as_uint(f);
    return (u + 0x7FFFu + ((u >> 16) & 1u)) >> 16;
}

// ---- phase 1: (N,C,H,W) f32 -> (N,HW,C) bf16 packed as uint pairs ----
__global__ __launch_bounds__(256) void repack_kernel(
    const float* __restrict__ img, unsigned int* __restrict__ ws)
{
    const int hw = blockIdx.x * 256 + threadIdx.x;
    const int n  = blockIdx.y;
    const float* src = img + (size_t)n * CC * HWSZ + hw;

    unsigned int buf[CC / 2];
    #pragma unroll
    for (int c2 = 0; c2 < CC / 2; ++c2) {
        float f0 = src[(size_t)(2 * c2) * HWSZ];
        float f1 = src[(size_t)(2 * c2 + 1) * HWSZ];
        buf[c2] = bf16rne(f0) | (bf16rne(f1) << 16);
    }
    uint4* dst = (uint4*)(ws + ((size_t)n * HWSZ + hw) * (CC / 2));
    #pragma unroll
    for (int k = 0; k < CC / 8; ++k)
        dst[k] = make_uint4(buf[4 * k], buf[4 * k + 1], buf[4 * k + 2], buf[4 * k + 3]);
}

// ---- phase 2: gather channels-last runs ----
__global__ __launch_bounds__(256) void sample_cl_kernel(
    const unsigned int* __restrict__ ws,   // (N, HW, C) bf16 pairs
    const float* __restrict__ points,      // (N, P, 2)
    float* __restrict__ out)               // (N, C, P)
{
    const int p = blockIdx.x * 256 + threadIdx.x;
    const int n = blockIdx.y;

    float2 pt = ((const float2*)points)[(size_t)n * PP + p];
    float x = ((pt.x + 1.0f) * (float)WW - 1.0f) * 0.5f;
    float y = ((pt.y + 1.0f) * (float)HH - 1.0f) * 0.5f;

    float x0f = floorf(x);
    float y0f = floorf(y);
    float fx = x - x0f;
    float fy = y - y0f;
    int x0 = (int)x0f;
    int y0 = (int)y0f;
    int x1 = x0 + 1;
    int y1 = y0 + 1;

    bool vx0 = (x0 >= 0) && (x0 < WW);
    bool vx1 = (x1 >= 0) && (x1 < WW);
    bool vy0 = (y0 >= 0) && (y0 < HH);
    bool vy1 = (y1 >= 0) && (y1 < HH);

    float wa = (1.0f - fx) * (1.0f - fy);  // (y0, x0)
    float wb = (1.0f - fx) * fy;           // (y1, x0)
    float wc = fx * (1.0f - fy);           // (y0, x1)
    float wd = fx * fy;                    // (y1, x1)

    wa = (vx0 && vy0) ? wa : 0.0f;
    wb = (vx0 && vy1) ? wb : 0.0f;
    wc = (vx1 && vy0) ? wc : 0.0f;
    wd = (vx1 && vy1) ? wd : 0.0f;

    int cx0 = min(max(x0, 0), WW - 1);
    int cx1 = min(max(x1, 0), WW - 1);
    int cy0 = min(max(y0, 0), HH - 1);
    int cy1 = min(max(y1, 0), HH - 1);

    const unsigned int* base = ws + (size_t)n * HWSZ * (CC / 2);
    const uint4* pa = (const uint4*)(base + (size_t)(cy0 * WW + cx0) * (CC / 2));
    const uint4* pb = (const uint4*)(base + (size_t)(cy1 * WW + cx0) * (CC / 2));
    const uint4* pc = (const uint4*)(base + (size_t)(cy0 * WW + cx1) * (CC / 2));
    const uint4* pd = (const uint4*)(base + (size_t)(cy1 * WW + cx1) * (CC / 2));

    float* outp = out + ((size_t)n * CC) * PP + p;

    #pragma unroll
    for (int k = 0; k < CC / 8; ++k) {   // 8 channels per iter
        uint4 A = pa[k], B = pb[k], C = pc[k], D = pd[k];
        const unsigned int aw[4] = {A.x, A.y, A.z, A.w};
        const unsigned int bw[4] = {B.x, B.y, B.z, B.w};
        const unsigned int cw[4] = {C.x, C.y, C.z, C.w};
        const unsigned int dw[4] = {D.x, D.y, D.z, D.w};
        #pragma unroll
        for (int j = 0; j < 4; ++j) {    // each uint = 2 channels
            float a0 = __uint_as_float(aw[j] << 16);
            float a1 = __uint_as_float(aw[j] & 0xFFFF0000u);
            float b0 = __uint_as_float(bw[j] << 16);
            float b1 = __uint_as_float(bw[j] & 0xFFFF0000u);
            float c0 = __uint_as_float(cw[j] << 16);
            float c1 = __uint_as_float(cw[j] & 0xFFFF0000u);
            float d0 = __uint_as_float(dw[j] << 16);
            float d1 = __uint_as_float(dw[j] & 0xFFFF0000u);
            float v0 = a0 * wa + b0 * wb + c0 * wc + d0 * wd;
            float v1 = a1 * wa + b1 * wb + c1 * wc + d1 * wd;
            int ch = k * 8 + j * 2;
            __builtin_nontemporal_store(v0, outp + (size_t)ch * PP);
            __builtin_nontemporal_store(v1, outp + (size_t)(ch + 1) * PP);
        }
    }
}

// ---- fallback (round-2 kernel) if ws is too small ----
__global__ __launch_bounds__(256) void grid_sample_fallback(
    const float* __restrict__ img,
    const float* __restrict__ points,
    float* __restrict__ out)
{
    const int p  = blockIdx.x * 256 + threadIdx.x;
    const int c0 = blockIdx.y * 2;
    const int n  = blockIdx.z;

    float2 pt = ((const float2*)points)[(size_t)n * PP + p];
    float x = ((pt.x + 1.0f) * (float)WW - 1.0f) * 0.5f;
    float y = ((pt.y + 1.0f) * (float)HH - 1.0f) * 0.5f;
    float x0f = floorf(x), y0f = floorf(y);
    float fx = x - x0f, fy = y - y0f;
    int x0 = (int)x0f, y0 = (int)y0f, x1 = x0 + 1, y1 = y0 + 1;
    bool vx0 = (x0 >= 0) && (x0 < WW), vx1 = (x1 >= 0) && (x1 < WW);
    bool vy0 = (y0 >= 0) && (y0 < HH), vy1 = (y1 >= 0) && (y1 < HH);
    float wa = (1.0f - fx) * (1.0f - fy), wb = (1.0f - fx) * fy;
    float wc = fx * (1.0f - fy), wd = fx * fy;
    wa = (vx0 && vy0) ? wa : 0.0f;
    wb = (vx0 && vy1) ? wb : 0.0f;
    wc = (vx1 && vy0) ? wc : 0.0f;
    wd = (vx1 && vy1) ? wd : 0.0f;
    int cx0 = min(max(x0, 0), WW - 1), cx1 = min(max(x1, 0), WW - 1);
    int cy0 = min(max(y0, 0), HH - 1), cy1 = min(max(y1, 0), HH - 1);
    int ia = cy0 * WW + cx0, ib = cy1 * WW + cx0;
    int ic = cy0 * WW + cx1, id = cy1 * WW + cx1;
    const float* plane = img + ((size_t)(n * CC + c0)) * HWSZ;
    float* outp = out + ((size_t)(n * CC + c0)) * PP + p;
    #pragma unroll
    for (int k = 0; k < 2; ++k) {
        float v = plane[ia] * wa + plane[ib] * wb + plane[ic] * wc + plane[id] * wd;
        __builtin_nontemporal_store(v, outp);
        plane += HWSZ;
        outp  += PP;
    }
}

extern "C" void kernel_launch(void* const* d_in, const int* in_sizes, int n_in,
                              void* d_out, int out_size, void* d_ws, size_t ws_size,
                              hipStream_t stream) {
    const float* img = (const float*)d_in[0];
    const float* points = (const float*)d_in[1];
    float* out = (float*)d_out;

    const size_t ws_needed = (size_t)8 * HWSZ * CC * 2;  // 67,108,864 B bf16
    if (ws_size >= ws_needed) {
        unsigned int* ws = (unsigned int*)d_ws;
        dim3 g1(HWSZ / 256, 8);
        repack_kernel<<<g1, 256, 0, stream>>>(img, ws);
        dim3 g2(PP / 256, 8);
        sample_cl_kernel<<<g2, 256, 0, stream>>>(ws, points, out);
    } else {
        dim3 g(PP / 256, CC / 2, 8);
        grid_sample_fallback<<<g, 256, 0, stream>>>(img, points, out);
    }
}

// Round 4
// 166.560 us; speedup vs baseline: 9.2133x; 1.8275x over previous
//
#include <hip/hip_runtime.h>

// BilinearGridSample: img (N=8, C=64, H=256, W=256) f32, points (N,384,384,2) f32
// out (N, C, 384*384) f32.  mmcv bilinear_grid_sample, align_corners=False.
//
// Phase-split channels-last design:
//  (1) repack img -> ws[n][cg][hw][32ch] bf16 (cg = channel group of 32).
//      One corner gather = 64 B = exactly one cache line, fully consumed.
//  (2) sample kernel: 16 phases q=(n,cg), each pinned to XCD q%8 via the
//      bid%8 round-robin dispatch heuristic. Per-phase footprint 4.2 MB ~= one
//      XCD L2 -> gather re-reads (mean ~9x/line) become L2 hits instead of
//      HBM traffic (round-3: 754 MB fetch vs 67 MB unique).

#define NN 8
#define CC 64
#define HH 256
#define WW 256
#define HWSZ (HH * WW)
#define PP (384 * 384)      // 147456
#define NCHUNK (PP / 256)   // 576 point-chunks per phase
#define NQ (NN * 2)         // 16 phases

__device__ __forceinline__ unsigned int bf16rne(float f) {
    unsigned int u = __float_as_uint(f);
    return (u + 0x7FFFu + ((u >> 16) & 1u)) >> 16;
}

// ---- phase 1: (N,C,H,W) f32 -> ws[(n*2+cg)][hw][32ch] bf16 ----
__global__ __launch_bounds__(256) void repack_kernel(
    const float* __restrict__ img, unsigned int* __restrict__ ws)
{
    const int hw = blockIdx.x * 256 + threadIdx.x;
    const int n  = blockIdx.y;
    const float* src = img + (size_t)n * CC * HWSZ + hw;

    unsigned int buf[CC / 2];
    #pragma unroll
    for (int c2 = 0; c2 < CC / 2; ++c2) {
        float f0 = src[(size_t)(2 * c2) * HWSZ];
        float f1 = src[(size_t)(2 * c2 + 1) * HWSZ];
        buf[c2] = bf16rne(f0) | (bf16rne(f1) << 16);
    }
    #pragma unroll
    for (int cg = 0; cg < 2; ++cg) {
        uint4* dst = (uint4*)(ws + ((size_t)(n * 2 + cg) * HWSZ + hw) * 16);
        #pragma unroll
        for (int k = 0; k < 4; ++k)
            dst[k] = make_uint4(buf[cg * 16 + 4 * k],     buf[cg * 16 + 4 * k + 1],
                                buf[cg * 16 + 4 * k + 2], buf[cg * 16 + 4 * k + 3]);
    }
}

// ---- phase 2: XCD-pinned gather, one (point, cgroup) per thread ----
__global__ __launch_bounds__(256) void sample_cl_kernel(
    const unsigned int* __restrict__ ws,   // (NQ, HW, 16 uints)
    const float* __restrict__ points,      // (N, P, 2)
    float* __restrict__ out)               // (N, C, P)
{
    const int bid  = blockIdx.x;           // 0 .. NQ*NCHUNK-1
    const int xcd  = bid & 7;
    const int seq  = bid >> 3;             // 0 .. 2*NCHUNK-1
    const int q    = xcd + 8 * (seq / NCHUNK);
    const int chunk = seq % NCHUNK;
    const int n  = q >> 1;
    const int cg = q & 1;
    const int p  = chunk * 256 + threadIdx.x;

    float2 pt = ((const float2*)points)[(size_t)n * PP + p];
    float x = ((pt.x + 1.0f) * (float)WW - 1.0f) * 0.5f;
    float y = ((pt.y + 1.0f) * (float)HH - 1.0f) * 0.5f;

    float x0f = floorf(x);
    float y0f = floorf(y);
    float fx = x - x0f;
    float fy = y - y0f;
    int x0 = (int)x0f;
    int y0 = (int)y0f;
    int x1 = x0 + 1;
    int y1 = y0 + 1;

    bool vx0 = (x0 >= 0) && (x0 < WW);
    bool vx1 = (x1 >= 0) && (x1 < WW);
    bool vy0 = (y0 >= 0) && (y0 < HH);
    bool vy1 = (y1 >= 0) && (y1 < HH);

    float wa = (1.0f - fx) * (1.0f - fy);  // (y0, x0)
    float wb = (1.0f - fx) * fy;           // (y1, x0)
    float wc = fx * (1.0f - fy);           // (y0, x1)
    float wd = fx * fy;                    // (y1, x1)

    wa = (vx0 && vy0) ? wa : 0.0f;
    wb = (vx0 && vy1) ? wb : 0.0f;
    wc = (vx1 && vy0) ? wc : 0.0f;
    wd = (vx1 && vy1) ? wd : 0.0f;

    int cx0 = min(max(x0, 0), WW - 1);
    int cx1 = min(max(x1, 0), WW - 1);
    int cy0 = min(max(y0, 0), HH - 1);
    int cy1 = min(max(y1, 0), HH - 1);

    const uint4* base = (const uint4*)ws + (size_t)q * HWSZ * 4;
    const uint4* pa = base + (size_t)(cy0 * WW + cx0) * 4;
    const uint4* pb = base + (size_t)(cy1 * WW + cx0) * 4;
    const uint4* pc = base + (size_t)(cy0 * WW + cx1) * 4;
    const uint4* pd = base + (size_t)(cy1 * WW + cx1) * 4;

    float* outp = out + ((size_t)n * CC + cg * 32) * PP + p;

    #pragma unroll
    for (int k = 0; k < 4; ++k) {   // 8 channels per iter
        uint4 A = pa[k], B = pb[k], C = pc[k], D = pd[k];
        const unsigned int aw[4] = {A.x, A.y, A.z, A.w};
        const unsigned int bw[4] = {B.x, B.y, B.z, B.w};
        const unsigned int cw[4] = {C.x, C.y, C.z, C.w};
        const unsigned int dw[4] = {D.x, D.y, D.z, D.w};
        #pragma unroll
        for (int j = 0; j < 4; ++j) {    // each uint = 2 channels
            float a0 = __uint_as_float(aw[j] << 16);
            float a1 = __uint_as_float(aw[j] & 0xFFFF0000u);
            float b0 = __uint_as_float(bw[j] << 16);
            float b1 = __uint_as_float(bw[j] & 0xFFFF0000u);
            float c0 = __uint_as_float(cw[j] << 16);
            float c1 = __uint_as_float(cw[j] & 0xFFFF0000u);
            float d0 = __uint_as_float(dw[j] << 16);
            float d1 = __uint_as_float(dw[j] & 0xFFFF0000u);
            float v0 = a0 * wa + b0 * wb + c0 * wc + d0 * wd;
            float v1 = a1 * wa + b1 * wb + c1 * wc + d1 * wd;
            int ch = k * 8 + j * 2;
            __builtin_nontemporal_store(v0, outp + (size_t)ch * PP);
            __builtin_nontemporal_store(v1, outp + (size_t)(ch + 1) * PP);
        }
    }
}

// ---- fallback (round-2 kernel) if ws is too small ----
__global__ __launch_bounds__(256) void grid_sample_fallback(
    const float* __restrict__ img,
    const float* __restrict__ points,
    float* __restrict__ out)
{
    const int p  = blockIdx.x * 256 + threadIdx.x;
    const int c0 = blockIdx.y * 2;
    const int n  = blockIdx.z;

    float2 pt = ((const float2*)points)[(size_t)n * PP + p];
    float x = ((pt.x + 1.0f) * (float)WW - 1.0f) * 0.5f;
    float y = ((pt.y + 1.0f) * (float)HH - 1.0f) * 0.5f;
    float x0f = floorf(x), y0f = floorf(y);
    float fx = x - x0f, fy = y - y0f;
    int x0 = (int)x0f, y0 = (int)y0f, x1 = x0 + 1, y1 = y0 + 1;
    bool vx0 = (x0 >= 0) && (x0 < WW), vx1 = (x1 >= 0) && (x1 < WW);
    bool vy0 = (y0 >= 0) && (y0 < HH), vy1 = (y1 >= 0) && (y1 < HH);
    float wa = (1.0f - fx) * (1.0f - fy), wb = (1.0f - fx) * fy;
    float wc = fx * (1.0f - fy), wd = fx * fy;
    wa = (vx0 && vy0) ? wa : 0.0f;
    wb = (vx0 && vy1) ? wb : 0.0f;
    wc = (vx1 && vy0) ? wc : 0.0f;
    wd = (vx1 && vy1) ? wd : 0.0f;
    int cx0 = min(max(x0, 0), WW - 1), cx1 = min(max(x1, 0), WW - 1);
    int cy0 = min(max(y0, 0), HH - 1), cy1 = min(max(y1, 0), HH - 1);
    int ia = cy0 * WW + cx0, ib = cy1 * WW + cx0;
    int ic = cy0 * WW + cx1, id = cy1 * WW + cx1;
    const float* plane = img + ((size_t)(n * CC + c0)) * HWSZ;
    float* outp = out + ((size_t)(n * CC + c0)) * PP + p;
    #pragma unroll
    for (int k = 0; k < 2; ++k) {
        float v = plane[ia] * wa + plane[ib] * wb + plane[ic] * wc + plane[id] * wd;
        __builtin_nontemporal_store(v, outp);
        plane += HWSZ;
        outp  += PP;
    }
}

extern "C" void kernel_launch(void* const* d_in, const int* in_sizes, int n_in,
                              void* d_out, int out_size, void* d_ws, size_t ws_size,
                              hipStream_t stream) {
    const float* img = (const float*)d_in[0];
    const float* points = (const float*)d_in[1];
    float* out = (float*)d_out;

    const size_t ws_needed = (size_t)NN * HWSZ * CC * 2;  // 67,108,864 B bf16
    if (ws_size >= ws_needed) {
        unsigned int* ws = (unsigned int*)d_ws;
        dim3 g1(HWSZ / 256, NN);
        repack_kernel<<<g1, 256, 0, stream>>>(img, ws);
        dim3 g2(NQ * NCHUNK);  // 9216 blocks, 1D for XCD pinning
        sample_cl_kernel<<<g2, 256, 0, stream>>>(ws, points, out);
    } else {
        dim3 g(PP / 256, CC / 2, NN);
        grid_sample_fallback<<<g, 256, 0, stream>>>(img, points, out);
    }
}

// Round 5
// 130.718 us; speedup vs baseline: 11.7395x; 1.2742x over previous
//
#include <hip/hip_runtime.h>

// BilinearGridSample: img (N=8, C=64, H=256, W=256) f32, points (N,384,384,2) f32
// out (N, C, 384*384) f32.  mmcv bilinear_grid_sample, align_corners=False.
//
// Phase-split channels-last design:
//  (1) repack img -> ws[n][cg][hw][32ch] bf16 (cg = channel group of 32).
//      One corner gather = 64 B line-run, fully consumed.
//  (2) sample: 16 phases q=(n,cg) pinned to XCD q%8 (bid%8 round-robin
//      heuristic); per-phase footprint 4 MiB = one XCD L2.
//      NEW (round 5): 4 lanes cooperate on one point — thread=(point,quarter),
//      each gather inst reads 16B/lane with 4 consecutive lanes covering one
//      64B corner run -> 16 unique lines/inst instead of 64 -> 4x less
//      texture-addresser serialization (was ~60us of the ~115us sample time).

#define NN 8
#define CC 64
#define HH 256
#define WW 256
#define HWSZ (HH * WW)
#define PP (384 * 384)      // 147456
#define CHUNKS (PP / 64)    // 2304 point-chunks (64 points/block) per phase
#define NQ (NN * 2)         // 16 phases

__device__ __forceinline__ unsigned int bf16rne(float f) {
    unsigned int u = __float_as_uint(f);
    return (u + 0x7FFFu + ((u >> 16) & 1u)) >> 16;
}

// ---- phase 1: (N,C,H,W) f32 -> ws[(n*2+cg)][hw][32ch] bf16 ----
__global__ __launch_bounds__(256) void repack_kernel(
    const float* __restrict__ img, unsigned int* __restrict__ ws)
{
    const int hw = blockIdx.x * 256 + threadIdx.x;
    const int n  = blockIdx.y;
    const float* src = img + (size_t)n * CC * HWSZ + hw;

    unsigned int buf[CC / 2];
    #pragma unroll
    for (int c2 = 0; c2 < CC / 2; ++c2) {
        float f0 = src[(size_t)(2 * c2) * HWSZ];
        float f1 = src[(size_t)(2 * c2 + 1) * HWSZ];
        buf[c2] = bf16rne(f0) | (bf16rne(f1) << 16);
    }
    #pragma unroll
    for (int cg = 0; cg < 2; ++cg) {
        uint4* dst = (uint4*)(ws + ((size_t)(n * 2 + cg) * HWSZ + hw) * 16);
        #pragma unroll
        for (int k = 0; k < 4; ++k)
            dst[k] = make_uint4(buf[cg * 16 + 4 * k],     buf[cg * 16 + 4 * k + 1],
                                buf[cg * 16 + 4 * k + 2], buf[cg * 16 + 4 * k + 3]);
    }
}

// ---- phase 2: XCD-pinned gather; 4 lanes per point (one 16B quarter each) ----
__global__ __launch_bounds__(256) void sample_cl_kernel(
    const unsigned int* __restrict__ ws,   // (NQ, HW, 16 uints)
    const float* __restrict__ points,      // (N, P, 2)
    float* __restrict__ out)               // (N, C, P)
{
    const int bid  = blockIdx.x;           // 0 .. NQ*CHUNKS-1
    const int xcd  = bid & 7;
    const int seq  = bid >> 3;             // 0 .. 2*CHUNKS-1
    const int q    = xcd + 8 * (seq / CHUNKS);   // phase 0..15
    const int chunk = seq % CHUNKS;
    const int n  = q >> 1;
    const int cg = q & 1;
    const int qt = threadIdx.x & 3;              // channel quarter (8 ch)
    const int p  = chunk * 64 + (threadIdx.x >> 2);

    float2 pt = ((const float2*)points)[(size_t)n * PP + p];
    float x = ((pt.x + 1.0f) * (float)WW - 1.0f) * 0.5f;
    float y = ((pt.y + 1.0f) * (float)HH - 1.0f) * 0.5f;

    float x0f = floorf(x);
    float y0f = floorf(y);
    float fx = x - x0f;
    float fy = y - y0f;
    int x0 = (int)x0f;
    int y0 = (int)y0f;
    int x1 = x0 + 1;
    int y1 = y0 + 1;

    bool vx0 = (x0 >= 0) && (x0 < WW);
    bool vx1 = (x1 >= 0) && (x1 < WW);
    bool vy0 = (y0 >= 0) && (y0 < HH);
    bool vy1 = (y1 >= 0) && (y1 < HH);

    float wa = (1.0f - fx) * (1.0f - fy);  // (y0, x0)
    float wb = (1.0f - fx) * fy;           // (y1, x0)
    float wc = fx * (1.0f - fy);           // (y0, x1)
    float wd = fx * fy;                    // (y1, x1)

    wa = (vx0 && vy0) ? wa : 0.0f;
    wb = (vx0 && vy1) ? wb : 0.0f;
    wc = (vx1 && vy0) ? wc : 0.0f;
    wd = (vx1 && vy1) ? wd : 0.0f;

    int cx0 = min(max(x0, 0), WW - 1);
    int cx1 = min(max(x1, 0), WW - 1);
    int cy0 = min(max(y0, 0), HH - 1);
    int cy1 = min(max(y1, 0), HH - 1);

    const uint4* base = (const uint4*)ws + (size_t)q * (HWSZ * 4) + qt;
    const uint4* pa = base + (size_t)(cy0 * WW + cx0) * 4;
    const uint4* pb = base + (size_t)(cy1 * WW + cx0) * 4;
    const uint4* pc = base + (size_t)(cy0 * WW + cx1) * 4;
    const uint4* pd = base + (size_t)(cy1 * WW + cx1) * 4;

    uint4 A = *pa;
    uint4 B = *pb;
    uint4 C = *pc;
    uint4 D = *pd;

    // this thread owns channels cg*32 + qt*8 + [0,8)
    float* outp = out + ((size_t)(n * CC) + cg * 32 + qt * 8) * PP + p;

    const unsigned int aw[4] = {A.x, A.y, A.z, A.w};
    const unsigned int bw[4] = {B.x, B.y, B.z, B.w};
    const unsigned int cw[4] = {C.x, C.y, C.z, C.w};
    const unsigned int dw[4] = {D.x, D.y, D.z, D.w};
    #pragma unroll
    for (int j = 0; j < 4; ++j) {    // each uint = 2 channels
        float a0 = __uint_as_float(aw[j] << 16);
        float a1 = __uint_as_float(aw[j] & 0xFFFF0000u);
        float b0 = __uint_as_float(bw[j] << 16);
        float b1 = __uint_as_float(bw[j] & 0xFFFF0000u);
        float c0 = __uint_as_float(cw[j] << 16);
        float c1 = __uint_as_float(cw[j] & 0xFFFF0000u);
        float d0 = __uint_as_float(dw[j] << 16);
        float d1 = __uint_as_float(dw[j] & 0xFFFF0000u);
        float v0 = a0 * wa + b0 * wb + c0 * wc + d0 * wd;
        float v1 = a1 * wa + b1 * wb + c1 * wc + d1 * wd;
        __builtin_nontemporal_store(v0, outp + (size_t)(2 * j) * PP);
        __builtin_nontemporal_store(v1, outp + (size_t)(2 * j + 1) * PP);
    }
}

// ---- fallback (round-2 kernel) if ws is too small ----
__global__ __launch_bounds__(256) void grid_sample_fallback(
    const float* __restrict__ img,
    const float* __restrict__ points,
    float* __restrict__ out)
{
    const int p  = blockIdx.x * 256 + threadIdx.x;
    const int c0 = blockIdx.y * 2;
    const int n  = blockIdx.z;

    float2 pt = ((const float2*)points)[(size_t)n * PP + p];
    float x = ((pt.x + 1.0f) * (float)WW - 1.0f) * 0.5f;
    float y = ((pt.y + 1.0f) * (float)HH - 1.0f) * 0.5f;
    float x0f = floorf(x), y0f = floorf(y);
    float fx = x - x0f, fy = y - y0f;
    int x0 = (int)x0f, y0 = (int)y0f, x1 = x0 + 1, y1 = y0 + 1;
    bool vx0 = (x0 >= 0) && (x0 < WW), vx1 = (x1 >= 0) && (x1 < WW);
    bool vy0 = (y0 >= 0) && (y0 < HH), vy1 = (y1 >= 0) && (y1 < HH);
    float wa = (1.0f - fx) * (1.0f - fy), wb = (1.0f - fx) * fy;
    float wc = fx * (1.0f - fy), wd = fx * fy;
    wa = (vx0 && vy0) ? wa : 0.0f;
    wb = (vx0 && vy1) ? wb : 0.0f;
    wc = (vx1 && vy0) ? wc : 0.0f;
    wd = (vx1 && vy1) ? wd : 0.0f;
    int cx0 = min(max(x0, 0), WW - 1), cx1 = min(max(x1, 0), WW - 1);
    int cy0 = min(max(y0, 0), HH - 1), cy1 = min(max(y1, 0), HH - 1);
    int ia = cy0 * WW + cx0, ib = cy1 * WW + cx0;
    int ic = cy0 * WW + cx1, id = cy1 * WW + cx1;
    const float* plane = img + ((size_t)(n * CC + c0)) * HWSZ;
    float* outp = out + ((size_t)(n * CC + c0)) * PP + p;
    #pragma unroll
    for (int k = 0; k < 2; ++k) {
        float v = plane[ia] * wa + plane[ib] * wb + plane[ic] * wc + plane[id] * wd;
        __builtin_nontemporal_store(v, outp);
        plane += HWSZ;
        outp  += PP;
    }
}

extern "C" void kernel_launch(void* const* d_in, const int* in_sizes, int n_in,
                              void* d_out, int out_size, void* d_ws, size_t ws_size,
                              hipStream_t stream) {
    const float* img = (const float*)d_in[0];
    const float* points = (const float*)d_in[1];
    float* out = (float*)d_out;

    const size_t ws_needed = (size_t)NN * HWSZ * CC * 2;  // 67,108,864 B bf16
    if (ws_size >= ws_needed) {
        unsigned int* ws = (unsigned int*)d_ws;
        dim3 g1(HWSZ / 256, NN);
        repack_kernel<<<g1, 256, 0, stream>>>(img, ws);
        dim3 g2(NQ * CHUNKS);  // 36,864 blocks, 1D for XCD pinning
        sample_cl_kernel<<<g2, 256, 0, stream>>>(ws, points, out);
    } else {
        dim3 g(PP / 256, CC / 2, NN);
        grid_sample_fallback<<<g, 256, 0, stream>>>(img, points, out);
    }
}